// Round 4
// baseline (559.944 us; speedup 1.0000x reference)
//
#include <hip/hip_runtime.h>
#include <hip/hip_bf16.h>

// BlockSparseLinear: y = x @ W^T + b
// Round 6: BARRIER-FREE GEMM. Problem-specific structure: each wave stages
// only its OWN 64 X-rows (wave-private LDS region -> own-vmcnt wait suffices),
// and W b-frags (16 B/lane, row-major) are read DIRECTLY from global (wb is
// 8 MB, L2/L3-hot, L1-shared across the block's waves). The only shared LDS
// operand is gone -> zero __syncthreads in the K-loop. Per-wave software
// pipeline: wait own DMA -> pull a-frags to VGPR -> issue b-loads (BEFORE next
// DMA: vmcnt retires in order, so b consumption must not be newer than the
// prefetch) -> lgkmcnt(0) (region provably free) -> MFMA ks0 -> DMA(kb+1)
// -> MFMA ks1. 16 free-running waves/CU hide residual latency (m114).
// Retained: 16B global_load_lds DMA, XOR chunk swizzle, bf16 pre-convert,
// XCD swizzle, TM=512 / 8 waves.

#define NTHREADS 512    // 8 waves
#define TM 512          // tokens per workgroup tile
#define KNZ 16          // nonzero col-blocks per row-block

typedef __attribute__((ext_vector_type(8))) short short8;    // bf16 x8 (16 B)
typedef __attribute__((ext_vector_type(4))) float floatx4;

__device__ __forceinline__ unsigned short f2bf(float f) {
    unsigned u = __float_as_uint(f);
    u += 0x7fffu + ((u >> 16) & 1u);
    return (unsigned short)(u >> 16);
}

// async 16B global -> LDS DMA; lds base must be wave-uniform, dest = base + lane*16
__device__ __forceinline__ void gl_lds_16(const void* g, void* l) {
    __builtin_amdgcn_global_load_lds(
        (const __attribute__((address_space(1))) unsigned int*)g,
        (__attribute__((address_space(3))) unsigned int*)l,
        16, 0, 0);
}

// ---- Kernel 1: fp32 -> bf16 conversion (x then w) ----
#define CVT_THREADS 256
__global__ __launch_bounds__(CVT_THREADS)
void cvt_kernel(const float* __restrict__ x, const float* __restrict__ w,
                unsigned short* __restrict__ xb, unsigned short* __restrict__ wb,
                int n_x8, int n_w8)
{
    int g = blockIdx.x * CVT_THREADS + threadIdx.x;
    const float* src;
    unsigned short* dst;
    if (g < n_x8) { src = x + (size_t)g * 8; dst = xb + (size_t)g * 8; }
    else {
        int h = g - n_x8;
        if (h >= n_w8) return;
        src = w + (size_t)h * 8; dst = wb + (size_t)h * 8;
    }
    floatx4 v0 = *(const floatx4*)(src);
    floatx4 v1 = *(const floatx4*)(src + 4);
    union { ushort4 u4[2]; short8 s8; } p;
    p.u4[0].x = f2bf(v0.x); p.u4[0].y = f2bf(v0.y);
    p.u4[0].z = f2bf(v0.z); p.u4[0].w = f2bf(v0.w);
    p.u4[1].x = f2bf(v1.x); p.u4[1].y = f2bf(v1.y);
    p.u4[1].z = f2bf(v1.z); p.u4[1].w = f2bf(v1.w);
    *(short8*)dst = p.s8;
}

// ---- Kernel 2: bf16 MFMA GEMM, barrier-free, wave-private X staging ----
__global__ __launch_bounds__(NTHREADS, 4)   // VGPR<=128 -> 2 blocks/CU (LDS 64KB)
void bsl_mfma_bf16_kernel(const unsigned short* __restrict__ xb,
                          const unsigned short* __restrict__ wb,
                          const float* __restrict__ bias,
                          const int* __restrict__ col_idx,
                          float* __restrict__ out,
                          int n_tiles)
{
    // Per-wave private 8 KB regions (wave wv owns Xs[wv*4096 .. +4095]).
    // Unpadded (DMA dest = wave-uniform base + lane*16); chunk position is
    // XOR-swizzled via the per-lane GLOBAL source address.
    __shared__ unsigned short Xs[TM * 64];   // 64 KB total

    // XCD swizzle: give each XCD whole token-tile groups so its x-slab stays
    // hot in its private L2/L3 path.
    int id = blockIdx.x;
    int rb, tt;
    if ((n_tiles & 7) == 0) {
        int xcd  = id & 7;
        int slot = id >> 3;           // 0 .. 64*tpx-1 within XCD
        int tpx  = n_tiles >> 3;      // token tiles per XCD
        rb = slot & 63;
        tt = xcd * tpx + (slot >> 6);
    } else {
        rb = id & 63;
        tt = id >> 6;
    }

    const int tid  = threadIdx.x;
    const int lane = tid & 63;
    const int wv   = tid >> 6;       // 0..7
    const int l15  = lane & 15;
    const int l4   = lane >> 4;
    const int tok0 = tt * TM;
    const int lr   = lane >> 3;      // 0..7: row within a DMA wave-load
    const int lc   = lane & 7;       // 0..7: swizzled chunk slot

    floatx4 acc[4][4];
    #pragma unroll
    for (int i = 0; i < 4; ++i)
        #pragma unroll
        for (int j = 0; j < 4; ++j)
            acc[i][j] = (floatx4){0.f, 0.f, 0.f, 0.f};

    // Stage THIS WAVE's 64 X-rows of col-block cb into its private region.
    // 8 DMA ops; LDS slot holds global chunk c8 = (lane&7) ^ (row&7).
    auto dma_x = [&](int cb) {
        const unsigned short* xsrc = xb + (size_t)tok0 * 4096 + (size_t)cb * 64;
        #pragma unroll
        for (int j = 0; j < 8; ++j) {
            int row = wv * 64 + j * 8 + lr;
            int c8  = lc ^ (row & 7);
            gl_lds_16(xsrc + (size_t)row * 4096 + c8 * 8, &Xs[wv * 4096 + j * 512]);
        }
    };

    const int* ci = col_idx + rb * KNZ;
    // per-lane W base: row = l15 (low), col chunk = l4; nt adds 16 rows, ks adds 32 elems
    const size_t wlane = (size_t)l15 * 64 + (size_t)l4 * 8;

    // Prologue: prefetch kb=0 (8 vmem ops in flight).
    dma_x(ci[0]);

    for (int kb = 0; kb < KNZ; ++kb) {
        const unsigned short* wsrc = wb + (size_t)(rb * KNZ + kb) * 4096 + wlane;

        // Wait MY DMA(kb). Nothing older is live (previous b-loads were
        // consumed). No barrier: the region is wave-private.
        asm volatile("s_waitcnt vmcnt(0)" ::: "memory");
        __builtin_amdgcn_sched_barrier(0);

        // Pull ALL a-frags (both k-halves) to VGPR, freeing the LDS region.
        // Chunk c8k = ks*4 + l4 lives at swizzled offset (c8k ^ (l15&7))*8.
        short8 a0[4], a1[4];
        {
            const int sw0 = ((0 * 4 + l4) ^ (l15 & 7)) * 8;
            const int sw1 = ((1 * 4 + l4) ^ (l15 & 7)) * 8;
            #pragma unroll
            for (int mt = 0; mt < 4; ++mt)
                a0[mt] = *(const short8*)&Xs[(wv * 64 + mt * 16 + l15) * 64 + sw0];
            #pragma unroll
            for (int mt = 0; mt < 4; ++mt)
                a1[mt] = *(const short8*)&Xs[(wv * 64 + mt * 16 + l15) * 64 + sw1];
        }

        // Issue ALL b-loads now — BEFORE the next DMA. vmcnt retires in issue
        // order, so b consumption then never forces the prefetch to drain.
        short8 b0[4], b1[4];
        #pragma unroll
        for (int nt = 0; nt < 4; ++nt)
            b0[nt] = *(const short8*)(wsrc + nt * 1024);
        #pragma unroll
        for (int nt = 0; nt < 4; ++nt)
            b1[nt] = *(const short8*)(wsrc + nt * 1024 + 32);

        // a-frags COMPLETED in VGPR -> region free for overwrite.
        asm volatile("s_waitcnt lgkmcnt(0)" ::: "memory");
        __builtin_amdgcn_sched_barrier(0);

        // ks=0 MFMAs (waits only b0: vmcnt(4), b1 stays in flight).
        #pragma unroll
        for (int mt = 0; mt < 4; ++mt)
            #pragma unroll
            for (int nt = 0; nt < 4; ++nt)
                acc[mt][nt] = __builtin_amdgcn_mfma_f32_16x16x32_bf16(
                    a0[mt], b0[nt], acc[mt][nt], 0, 0, 0);

        // Prefetch next X tile into the (now free) private region; lands
        // during ks=1 MFMAs + next iteration's front matter.
        __builtin_amdgcn_sched_barrier(0);
        if (kb + 1 < KNZ) dma_x(ci[kb + 1]);
        __builtin_amdgcn_sched_barrier(0);

        // ks=1 MFMAs (waits b1: vmcnt(8) keeps the 8 DMA ops in flight).
        #pragma unroll
        for (int mt = 0; mt < 4; ++mt)
            #pragma unroll
            for (int nt = 0; nt < 4; ++nt)
                acc[mt][nt] = __builtin_amdgcn_mfma_f32_16x16x32_bf16(
                    a1[mt], b1[nt], acc[mt][nt], 0, 0, 0);
    }

    // Epilogue: C/D layout col = lane&15, row = (lane>>4)*4 + reg.
    const int ocol0 = rb * 64;
    #pragma unroll
    for (int nt = 0; nt < 4; ++nt) {
        const int col = ocol0 + nt * 16 + l15;
        const float bv = bias[col];
        #pragma unroll
        for (int mt = 0; mt < 4; ++mt) {
            const size_t trow = (size_t)tok0 + wv * 64 + mt * 16 + l4 * 4;
            float* op = out + trow * 4096 + col;
            #pragma unroll
            for (int r = 0; r < 4; ++r)
                op[(size_t)r * 4096] = acc[mt][nt][r] + bv;
        }
    }
}

// ---- Fallback (fp32 direct) if ws too small ---- (256 threads, TM=256)
#define TMF 256
#define NTF 256
#define XS_LD 72
#define WS_LD 72
__global__ __launch_bounds__(NTF)
void bsl_mfma_f32_kernel(const float* __restrict__ x,
                         const float* __restrict__ w,
                         const float* __restrict__ bias,
                         const int* __restrict__ col_idx,
                         float* __restrict__ out)
{
    __shared__ unsigned short Xs[TMF * XS_LD];
    __shared__ unsigned short Ws[64 * WS_LD];
    const int rb = blockIdx.x, tt = blockIdx.y;
    const int tid = threadIdx.x, lane = tid & 63, wv = tid >> 6;
    const int l15 = lane & 15, l4 = lane >> 4, tok0 = tt * TMF;
    floatx4 acc[4][4];
    #pragma unroll
    for (int i = 0; i < 4; ++i)
        #pragma unroll
        for (int j = 0; j < 4; ++j) acc[i][j] = (floatx4){0.f,0.f,0.f,0.f};
    for (int kb = 0; kb < KNZ; ++kb) {
        const int nz = rb * KNZ + kb;
        const int cb = col_idx[nz];
        const float* xsrc = x + (size_t)tok0 * 4096 + (size_t)cb * 64;
        const float* wsrc = w + (size_t)nz * 4096;
        __syncthreads();
        #pragma unroll
        for (int i = 0; i < 16; ++i) {
            int f = i * NTF + tid, row = f >> 4, c4 = f & 15;
            floatx4 v = *(const floatx4*)(xsrc + (size_t)row * 4096 + c4 * 4);
            ushort4 p; p.x=f2bf(v.x); p.y=f2bf(v.y); p.z=f2bf(v.z); p.w=f2bf(v.w);
            *(ushort4*)&Xs[row * XS_LD + c4 * 4] = p;
        }
        #pragma unroll
        for (int i = 0; i < 4; ++i) {
            int f = i * NTF + tid, row = f >> 4, c4 = f & 15;
            floatx4 v = *(const floatx4*)(wsrc + row * 64 + c4 * 4);
            ushort4 p; p.x=f2bf(v.x); p.y=f2bf(v.y); p.z=f2bf(v.z); p.w=f2bf(v.w);
            *(ushort4*)&Ws[row * WS_LD + c4 * 4] = p;
        }
        __syncthreads();
        #pragma unroll
        for (int ks = 0; ks < 2; ++ks) {
            const int k0 = ks * 32 + l4 * 8;
            short8 a[4], b[4];
            #pragma unroll
            for (int mt = 0; mt < 4; ++mt)
                a[mt] = *(const short8*)&Xs[(wv*64 + mt*16 + l15) * XS_LD + k0];
            #pragma unroll
            for (int nt = 0; nt < 4; ++nt)
                b[nt] = *(const short8*)&Ws[(nt*16 + l15) * WS_LD + k0];
            #pragma unroll
            for (int mt = 0; mt < 4; ++mt)
                #pragma unroll
                for (int nt = 0; nt < 4; ++nt)
                    acc[mt][nt] = __builtin_amdgcn_mfma_f32_16x16x32_bf16(
                        a[mt], b[nt], acc[mt][nt], 0, 0, 0);
        }
    }
    const int ocol0 = rb * 64;
    #pragma unroll
    for (int nt = 0; nt < 4; ++nt) {
        const int col = ocol0 + nt * 16 + l15;
        const float bv = bias[col];
        #pragma unroll
        for (int mt = 0; mt < 4; ++mt) {
            const size_t trow = (size_t)tok0 + wv * 64 + mt * 16 + l4 * 4;
            float* op = out + trow * 4096 + col;
            #pragma unroll
            for (int r = 0; r < 4; ++r)
                op[(size_t)r * 4096] = acc[mt][nt][r] + bv;
        }
    }
}

extern "C" void kernel_launch(void* const* d_in, const int* in_sizes, int n_in,
                              void* d_out, int out_size, void* d_ws, size_t ws_size,
                              hipStream_t stream) {
    const float* x       = (const float*)d_in[0];
    const float* w       = (const float*)d_in[1];
    const float* bias    = (const float*)d_in[2];
    const int*   col_idx = (const int*)d_in[4];
    float*       out     = (float*)d_out;

    const int n_x = in_sizes[0];
    const int n_w = in_sizes[1];
    const int n_tok = n_x / 4096;
    const size_t need = (size_t)(n_x + n_w) * 2;

    if (ws_size >= need && (n_tok % TM) == 0) {
        unsigned short* xb = (unsigned short*)d_ws;
        unsigned short* wb = xb + n_x;
        int n_x8 = n_x / 8, n_w8 = n_w / 8;
        int total = n_x8 + n_w8;
        cvt_kernel<<<(total + CVT_THREADS - 1) / CVT_THREADS, CVT_THREADS, 0, stream>>>(
            x, w, xb, wb, n_x8, n_w8);
        int n_tiles = n_tok / TM;
        bsl_mfma_bf16_kernel<<<64 * n_tiles, NTHREADS, 0, stream>>>(
            xb, wb, bias, col_idx, out, n_tiles);
    } else {
        dim3 grid(64, n_tok / TMF);
        bsl_mfma_f32_kernel<<<grid, NTF, 0, stream>>>(x, w, bias, col_idx, out);
    }
}

// Round 5
// 392.105 us; speedup vs baseline: 1.4280x; 1.4280x over previous
//
#include <hip/hip_runtime.h>
#include <hip/hip_bf16.h>

// BlockSparseLinear: y = x @ W^T + b
// Round 7: hybrid of round 5 (best, 100us) + round 6's valid half.
//  - W (the ONLY inter-wave-shared operand) staged in LDS, double-buffered
//    (2 x 8 KB), ONE 16B DMA per wave per kb.  [round-6's direct-global W
//    read amplified W traffic x8 -> 765 MB L2 fill -> 3x regression. revert.]
//  - X stays WAVE-PRIVATE: each wave DMAs only its own 64 rows and reads only
//    those -> no barrier needed for X, just own-wave vmcnt.
//  - ONE raw s_barrier per kb with COUNTED vmcnt (T4): issue W-DMA before the
//    8 X-DMA ops, then `s_waitcnt vmcnt(8)` retires exactly the W op while the
//    8 X ops stay in flight ACROSS the barrier (__syncthreads would drain
//    vmcnt(0) and kill the X prefetch - that was round 5's stall).
// Hazards: Ws[cur^1] overwrite is safe (all waves' reads of that buf finished
// before the PREVIOUS barrier); X region overwrite is wave-local (lgkmcnt(0)
// after a-frag reads precedes the DMA re-issue).
// Retained: 16B global_load_lds, XOR chunk swizzle (0 conflicts), bf16
// pre-convert, XCD swizzle, TM=512/8 waves, LDS 80 KB -> 2 blocks/CU.

#define NTHREADS 512    // 8 waves
#define TM 512          // tokens per workgroup tile
#define KNZ 16          // nonzero col-blocks per row-block

typedef __attribute__((ext_vector_type(8))) short short8;    // bf16 x8 (16 B)
typedef __attribute__((ext_vector_type(4))) float floatx4;

__device__ __forceinline__ unsigned short f2bf(float f) {
    unsigned u = __float_as_uint(f);
    u += 0x7fffu + ((u >> 16) & 1u);
    return (unsigned short)(u >> 16);
}

// async 16B global -> LDS DMA; lds base must be wave-uniform, dest = base + lane*16
__device__ __forceinline__ void gl_lds_16(const void* g, void* l) {
    __builtin_amdgcn_global_load_lds(
        (const __attribute__((address_space(1))) unsigned int*)g,
        (__attribute__((address_space(3))) unsigned int*)l,
        16, 0, 0);
}

// ---- Kernel 1: fp32 -> bf16 conversion (x then w) ----
#define CVT_THREADS 256
__global__ __launch_bounds__(CVT_THREADS)
void cvt_kernel(const float* __restrict__ x, const float* __restrict__ w,
                unsigned short* __restrict__ xb, unsigned short* __restrict__ wb,
                int n_x8, int n_w8)
{
    int g = blockIdx.x * CVT_THREADS + threadIdx.x;
    const float* src;
    unsigned short* dst;
    if (g < n_x8) { src = x + (size_t)g * 8; dst = xb + (size_t)g * 8; }
    else {
        int h = g - n_x8;
        if (h >= n_w8) return;
        src = w + (size_t)h * 8; dst = wb + (size_t)h * 8;
    }
    floatx4 v0 = *(const floatx4*)(src);
    floatx4 v1 = *(const floatx4*)(src + 4);
    union { ushort4 u4[2]; short8 s8; } p;
    p.u4[0].x = f2bf(v0.x); p.u4[0].y = f2bf(v0.y);
    p.u4[0].z = f2bf(v0.z); p.u4[0].w = f2bf(v0.w);
    p.u4[1].x = f2bf(v1.x); p.u4[1].y = f2bf(v1.y);
    p.u4[1].z = f2bf(v1.z); p.u4[1].w = f2bf(v1.w);
    *(short8*)dst = p.s8;
}

// ---- Kernel 2: bf16 MFMA GEMM, counted-vmcnt barrier, W dbuf + private X ----
__global__ __launch_bounds__(NTHREADS, 4)
void bsl_mfma_bf16_kernel(const unsigned short* __restrict__ xb,
                          const unsigned short* __restrict__ wb,
                          const float* __restrict__ bias,
                          const int* __restrict__ col_idx,
                          float* __restrict__ out,
                          int n_tiles)
{
    // X: per-wave private 8 KB regions. W: 2 x 8 KB double buffer.
    // Unpadded (DMA dest = wave-uniform base + lane*16); chunk position is
    // XOR-swizzled via the per-lane GLOBAL source address.
    __shared__ unsigned short Xs[TM * 64];      // 64 KB
    __shared__ unsigned short Ws[2][64 * 64];   // 16 KB -> 80 KB total

    // XCD swizzle: give each XCD whole token-tile groups (x-slab L2 locality).
    int id = blockIdx.x;
    int rb, tt;
    if ((n_tiles & 7) == 0) {
        int xcd  = id & 7;
        int slot = id >> 3;
        int tpx  = n_tiles >> 3;
        rb = slot & 63;
        tt = xcd * tpx + (slot >> 6);
    } else {
        rb = id & 63;
        tt = id >> 6;
    }

    const int tid  = threadIdx.x;
    const int lane = tid & 63;
    const int wv   = tid >> 6;       // 0..7
    const int l15  = lane & 15;
    const int l4   = lane >> 4;
    const int tok0 = tt * TM;
    const int lr   = lane >> 3;      // 0..7: row within a DMA wave-load
    const int lc   = lane & 7;       // 0..7: swizzled chunk slot

    floatx4 acc[4][4];
    #pragma unroll
    for (int i = 0; i < 4; ++i)
        #pragma unroll
        for (int j = 0; j < 4; ++j)
            acc[i][j] = (floatx4){0.f, 0.f, 0.f, 0.f};

    // Stage THIS WAVE's 64 X-rows of col-block cb into its private region (8 ops).
    auto dma_x = [&](int cb) {
        const unsigned short* xsrc = xb + (size_t)tok0 * 4096 + (size_t)cb * 64;
        #pragma unroll
        for (int j = 0; j < 8; ++j) {
            int row = wv * 64 + j * 8 + lr;
            int c8  = lc ^ (row & 7);
            gl_lds_16(xsrc + (size_t)row * 4096 + c8 * 8, &Xs[wv * 4096 + j * 512]);
        }
    };
    // Stage W block kb into buffer buf (1 op per wave; 8 waves cover 8 KB).
    auto dma_w = [&](int buf, int kb) {
        const unsigned short* wsrc = wb + (size_t)(rb * KNZ + kb) * 4096;
        int row = wv * 8 + lr;
        int c8  = lc ^ (row & 7);
        gl_lds_16(wsrc + row * 64 + c8 * 8, &Ws[buf][wv * 512]);
    };

    const int* ci = col_idx + rb * KNZ;

    // Prologue: W(0) first, then X(0). Retire W only (vmcnt(8)), publish it.
    dma_w(0, 0);
    dma_x(ci[0]);
    asm volatile("s_waitcnt vmcnt(8)" ::: "memory");   // W(0) landed; X(0) in flight
    __builtin_amdgcn_s_barrier();

    const int swA = (l4 ^ (l15 & 7)) * 8;          // ks=0 swizzled chunk offset
    const int swB = ((4 + l4) ^ (l15 & 7)) * 8;    // ks=1

    for (int kb = 0; kb < KNZ; ++kb) {
        const int cur = kb & 1;

        // Own X(kb) landed (only my 8 X ops are outstanding at loop top).
        asm volatile("s_waitcnt vmcnt(0)" ::: "memory");
        __builtin_amdgcn_sched_barrier(0);

        // Pull BOTH a-halves (frees X region) + b ks0 half to regs.
        short8 a0[4], a1[4], b0[4], b1[4];
        #pragma unroll
        for (int mt = 0; mt < 4; ++mt)
            a0[mt] = *(const short8*)&Xs[(wv * 64 + mt * 16 + l15) * 64 + swA];
        #pragma unroll
        for (int mt = 0; mt < 4; ++mt)
            a1[mt] = *(const short8*)&Xs[(wv * 64 + mt * 16 + l15) * 64 + swB];
        #pragma unroll
        for (int nt = 0; nt < 4; ++nt)
            b0[nt] = *(const short8*)&Ws[cur][(nt * 16 + l15) * 64 + swA];
        asm volatile("s_waitcnt lgkmcnt(0)" ::: "memory");  // X region free
        __builtin_amdgcn_sched_barrier(0);

        // Prefetch next tile: W (shared) FIRST, then X (private) -> the
        // pre-barrier vmcnt(8) retires exactly the W op.
        if (kb + 1 < KNZ) { dma_w(cur ^ 1, kb + 1); dma_x(ci[kb + 1]); }
        __builtin_amdgcn_sched_barrier(0);

        __builtin_amdgcn_s_setprio(1);
        #pragma unroll
        for (int mt = 0; mt < 4; ++mt)
            #pragma unroll
            for (int nt = 0; nt < 4; ++nt)
                acc[mt][nt] = __builtin_amdgcn_mfma_f32_16x16x32_bf16(
                    a0[mt], b0[nt], acc[mt][nt], 0, 0, 0);
        __builtin_amdgcn_s_setprio(0);

        #pragma unroll
        for (int nt = 0; nt < 4; ++nt)
            b1[nt] = *(const short8*)&Ws[cur][(nt * 16 + l15) * 64 + swB];
        asm volatile("s_waitcnt lgkmcnt(0)" ::: "memory");
        __builtin_amdgcn_sched_barrier(0);

        __builtin_amdgcn_s_setprio(1);
        #pragma unroll
        for (int mt = 0; mt < 4; ++mt)
            #pragma unroll
            for (int nt = 0; nt < 4; ++nt)
                acc[mt][nt] = __builtin_amdgcn_mfma_f32_16x16x32_bf16(
                    a1[mt], b1[nt], acc[mt][nt], 0, 0, 0);
        __builtin_amdgcn_s_setprio(0);

        if (kb + 1 < KNZ) {
            // Retire W(kb+1) only; the 8 X(kb+1) ops survive the barrier.
            asm volatile("s_waitcnt vmcnt(8)" ::: "memory");
            __builtin_amdgcn_s_barrier();          // publish W(kb+1)
        }
    }

    // Epilogue: C/D layout col = lane&15, row = (lane>>4)*4 + reg.
    const int ocol0 = rb * 64;
    #pragma unroll
    for (int nt = 0; nt < 4; ++nt) {
        const int col = ocol0 + nt * 16 + l15;
        const float bv = bias[col];
        #pragma unroll
        for (int mt = 0; mt < 4; ++mt) {
            const size_t trow = (size_t)tok0 + wv * 64 + mt * 16 + l4 * 4;
            float* op = out + trow * 4096 + col;
            #pragma unroll
            for (int r = 0; r < 4; ++r)
                op[(size_t)r * 4096] = acc[mt][nt][r] + bv;
        }
    }
}

// ---- Fallback (fp32 direct) if ws too small ---- (256 threads, TM=256)
#define TMF 256
#define NTF 256
#define XS_LD 72
#define WS_LD 72
__global__ __launch_bounds__(NTF)
void bsl_mfma_f32_kernel(const float* __restrict__ x,
                         const float* __restrict__ w,
                         const float* __restrict__ bias,
                         const int* __restrict__ col_idx,
                         float* __restrict__ out)
{
    __shared__ unsigned short Xs[TMF * XS_LD];
    __shared__ unsigned short Ws[64 * WS_LD];
    const int rb = blockIdx.x, tt = blockIdx.y;
    const int tid = threadIdx.x, lane = tid & 63, wv = tid >> 6;
    const int l15 = lane & 15, l4 = lane >> 4, tok0 = tt * TMF;
    floatx4 acc[4][4];
    #pragma unroll
    for (int i = 0; i < 4; ++i)
        #pragma unroll
        for (int j = 0; j < 4; ++j) acc[i][j] = (floatx4){0.f,0.f,0.f,0.f};
    for (int kb = 0; kb < KNZ; ++kb) {
        const int nz = rb * KNZ + kb;
        const int cb = col_idx[nz];
        const float* xsrc = x + (size_t)tok0 * 4096 + (size_t)cb * 64;
        const float* wsrc = w + (size_t)nz * 4096;
        __syncthreads();
        #pragma unroll
        for (int i = 0; i < 16; ++i) {
            int f = i * NTF + tid, row = f >> 4, c4 = f & 15;
            floatx4 v = *(const floatx4*)(xsrc + (size_t)row * 4096 + c4 * 4);
            ushort4 p; p.x=f2bf(v.x); p.y=f2bf(v.y); p.z=f2bf(v.z); p.w=f2bf(v.w);
            *(ushort4*)&Xs[row * XS_LD + c4 * 4] = p;
        }
        #pragma unroll
        for (int i = 0; i < 4; ++i) {
            int f = i * NTF + tid, row = f >> 4, c4 = f & 15;
            floatx4 v = *(const floatx4*)(wsrc + row * 64 + c4 * 4);
            ushort4 p; p.x=f2bf(v.x); p.y=f2bf(v.y); p.z=f2bf(v.z); p.w=f2bf(v.w);
            *(ushort4*)&Ws[row * WS_LD + c4 * 4] = p;
        }
        __syncthreads();
        #pragma unroll
        for (int ks = 0; ks < 2; ++ks) {
            const int k0 = ks * 32 + l4 * 8;
            short8 a[4], b[4];
            #pragma unroll
            for (int mt = 0; mt < 4; ++mt)
                a[mt] = *(const short8*)&Xs[(wv*64 + mt*16 + l15) * XS_LD + k0];
            #pragma unroll
            for (int nt = 0; nt < 4; ++nt)
                b[nt] = *(const short8*)&Ws[(nt*16 + l15) * WS_LD + k0];
            #pragma unroll
            for (int mt = 0; mt < 4; ++mt)
                #pragma unroll
                for (int nt = 0; nt < 4; ++nt)
                    acc[mt][nt] = __builtin_amdgcn_mfma_f32_16x16x32_bf16(
                        a[mt], b[nt], acc[mt][nt], 0, 0, 0);
        }
    }
    const int ocol0 = rb * 64;
    #pragma unroll
    for (int nt = 0; nt < 4; ++nt) {
        const int col = ocol0 + nt * 16 + l15;
        const float bv = bias[col];
        #pragma unroll
        for (int mt = 0; mt < 4; ++mt) {
            const size_t trow = (size_t)tok0 + wv * 64 + mt * 16 + l4 * 4;
            float* op = out + trow * 4096 + col;
            #pragma unroll
            for (int r = 0; r < 4; ++r)
                op[(size_t)r * 4096] = acc[mt][nt][r] + bv;
        }
    }
}

extern "C" void kernel_launch(void* const* d_in, const int* in_sizes, int n_in,
                              void* d_out, int out_size, void* d_ws, size_t ws_size,
                              hipStream_t stream) {
    const float* x       = (const float*)d_in[0];
    const float* w       = (const float*)d_in[1];
    const float* bias    = (const float*)d_in[2];
    const int*   col_idx = (const int*)d_in[4];
    float*       out     = (float*)d_out;

    const int n_x = in_sizes[0];
    const int n_w = in_sizes[1];
    const int n_tok = n_x / 4096;
    const size_t need = (size_t)(n_x + n_w) * 2;

    if (ws_size >= need && (n_tok % TM) == 0) {
        unsigned short* xb = (unsigned short*)d_ws;
        unsigned short* wb = xb + n_x;
        int n_x8 = n_x / 8, n_w8 = n_w / 8;
        int total = n_x8 + n_w8;
        cvt_kernel<<<(total + CVT_THREADS - 1) / CVT_THREADS, CVT_THREADS, 0, stream>>>(
            x, w, xb, wb, n_x8, n_w8);
        int n_tiles = n_tok / TM;
        bsl_mfma_bf16_kernel<<<64 * n_tiles, NTHREADS, 0, stream>>>(
            xb, wb, bias, col_idx, out, n_tiles);
    } else {
        dim3 grid(64, n_tok / TMF);
        bsl_mfma_f32_kernel<<<grid, NTF, 0, stream>>>(x, w, bias, col_idx, out);
    }
}

// Round 7
// 377.672 us; speedup vs baseline: 1.4826x; 1.0382x over previous
//
#include <hip/hip_runtime.h>
#include <hip/hip_bf16.h>

// BlockSparseLinear: y = x @ W^T + b
// Round 8 (resubmit — round-6 bench was an infra failure, no data; audit
// found no hang/fault path: uniform barriers, exact vmcnt bookkeeping,
// guarded prefetch addresses).
// X bypasses LDS entirely. Insight: X has ZERO intra-block reuse
// (each row belongs to one wave, each 16B chunk to one lane's fragment), so
// LDS staging of X was pure overhead (DMA + ds_read + the vmcnt drain that
// stalled every kb). A-fragments now load global->VGPR directly (16B/lane;
// lanes {0,16,32,48} cover 64B contiguous per row; a0+a1 consume full 128B
// lines). W keeps the round-5/7 treatment (the x8-shared operand): LDS,
// double-buffered, 1 DMA op/wave/kb, XOR-swizzled, 0 bank conflicts.
// Lock-step is load-bearing (round-7 lesson: loose schedules decohere the
// per-XCD X-stripe reuse; the 4MB slab is exactly L2-sized -> FETCH 212->479MB
// and 1.6x regression). So: ONE tight barrier per kb, counted vmcnt:
//   top: vmcnt(0) waits only my 8 a-loads (W already retired)
//   issue W-DMA(kb+1) -> ds_read b -> MFMA ks0 -> issue a0(kb+1) (regs freed
//   by ks0) -> MFMA ks1 -> issue a1(kb+1) -> vmcnt(8) retires W only ->
//   s_barrier (8 a-loads stay in flight ACROSS the barrier).
// LDS 80->16 KB; regs ~64 VGPR + 64 AGPR = 128 -> 4 waves/SIMD kept.

#define NTHREADS 512    // 8 waves
#define TM 512          // tokens per workgroup tile
#define KNZ 16          // nonzero col-blocks per row-block

typedef __attribute__((ext_vector_type(8))) short short8;    // bf16 x8 (16 B)
typedef __attribute__((ext_vector_type(4))) float floatx4;

__device__ __forceinline__ unsigned short f2bf(float f) {
    unsigned u = __float_as_uint(f);
    u += 0x7fffu + ((u >> 16) & 1u);
    return (unsigned short)(u >> 16);
}

// async 16B global -> LDS DMA; lds base must be wave-uniform, dest = base + lane*16
__device__ __forceinline__ void gl_lds_16(const void* g, void* l) {
    __builtin_amdgcn_global_load_lds(
        (const __attribute__((address_space(1))) unsigned int*)g,
        (__attribute__((address_space(3))) unsigned int*)l,
        16, 0, 0);
}

// ---- Kernel 1: fp32 -> bf16 conversion (x then w) ----
#define CVT_THREADS 256
__global__ __launch_bounds__(CVT_THREADS)
void cvt_kernel(const float* __restrict__ x, const float* __restrict__ w,
                unsigned short* __restrict__ xb, unsigned short* __restrict__ wb,
                int n_x8, int n_w8)
{
    int g = blockIdx.x * CVT_THREADS + threadIdx.x;
    const float* src;
    unsigned short* dst;
    if (g < n_x8) { src = x + (size_t)g * 8; dst = xb + (size_t)g * 8; }
    else {
        int h = g - n_x8;
        if (h >= n_w8) return;
        src = w + (size_t)h * 8; dst = wb + (size_t)h * 8;
    }
    floatx4 v0 = *(const floatx4*)(src);
    floatx4 v1 = *(const floatx4*)(src + 4);
    union { ushort4 u4[2]; short8 s8; } p;
    p.u4[0].x = f2bf(v0.x); p.u4[0].y = f2bf(v0.y);
    p.u4[0].z = f2bf(v0.z); p.u4[0].w = f2bf(v0.w);
    p.u4[1].x = f2bf(v1.x); p.u4[1].y = f2bf(v1.y);
    p.u4[1].z = f2bf(v1.z); p.u4[1].w = f2bf(v1.w);
    *(short8*)dst = p.s8;
}

// ---- Kernel 2: bf16 MFMA GEMM; direct-global A, LDS dbuf W, 1 barrier/kb ----
__global__ __launch_bounds__(NTHREADS, 4)
void bsl_mfma_bf16_kernel(const unsigned short* __restrict__ xb,
                          const unsigned short* __restrict__ wb,
                          const float* __restrict__ bias,
                          const int* __restrict__ col_idx,
                          float* __restrict__ out,
                          int n_tiles)
{
    __shared__ unsigned short Ws[2][64 * 64];   // 16 KB total

    // XCD swizzle: give each XCD whole token-tile groups (x-slab L2 locality).
    int id = blockIdx.x;
    int rb, tt;
    if ((n_tiles & 7) == 0) {
        int xcd  = id & 7;
        int slot = id >> 3;
        int tpx  = n_tiles >> 3;
        rb = slot & 63;
        tt = xcd * tpx + (slot >> 6);
    } else {
        rb = id & 63;
        tt = id >> 6;
    }

    const int tid  = threadIdx.x;
    const int lane = tid & 63;
    const int wv   = tid >> 6;       // 0..7
    const int l15  = lane & 15;
    const int l4   = lane >> 4;
    const int tok0 = tt * TM;
    const int lr   = lane >> 3;      // 0..7: row within the W DMA wave-load
    const int lc   = lane & 7;       // 0..7: swizzled chunk slot

    floatx4 acc[4][4];
    #pragma unroll
    for (int i = 0; i < 4; ++i)
        #pragma unroll
        for (int j = 0; j < 4; ++j)
            acc[i][j] = (floatx4){0.f, 0.f, 0.f, 0.f};

    // W block kb -> Ws[buf]; 1 DMA op per wave (8 waves cover 8 KB).
    // LDS slot holds global chunk c8 = (lane&7) ^ (row&7)  (XOR swizzle).
    auto dma_w = [&](int buf, int kb) {
        const unsigned short* wsrc = wb + (size_t)(rb * KNZ + kb) * 4096;
        int row = wv * 8 + lr;
        int c8  = lc ^ (row & 7);
        gl_lds_16(wsrc + row * 64 + c8 * 8, &Ws[buf][wv * 512]);
    };

    const int* ci = col_idx + rb * KNZ;

    // Per-lane A base: row = tok0 + wv*64 + l15 (+16 per mt), k-chunk = l4
    // (+4 per ks). addr(el) = row*4096 + cb*64 + ks*32 + l4*8.
    const unsigned short* xrow =
        xb + ((size_t)tok0 + (size_t)wv * 64 + l15) * 4096 + l4 * 8;

    short8 a0[4], a1[4];

    // Prologue: W(0) DMA first, then the 8 a(0) loads; retire W only.
    dma_w(0, 0);
    {
        const unsigned short* xp = xrow + (size_t)ci[0] * 64;
        #pragma unroll
        for (int mt = 0; mt < 4; ++mt)
            a0[mt] = *(const short8*)(xp + mt * 65536);
        #pragma unroll
        for (int mt = 0; mt < 4; ++mt)
            a1[mt] = *(const short8*)(xp + mt * 65536 + 32);
    }
    asm volatile("s_waitcnt vmcnt(8)" ::: "memory");   // W(0) landed; a(0) fly
    __builtin_amdgcn_sched_barrier(0);
    __builtin_amdgcn_s_barrier();                      // publish W(0)

    const int swA = (l4 ^ (l15 & 7)) * 8;          // ks=0 swizzled W chunk
    const int swB = ((4 + l4) ^ (l15 & 7)) * 8;    // ks=1

    for (int kb = 0; kb < KNZ; ++kb) {
        const int cur = kb & 1;
        const bool has_next = (kb + 1 < KNZ);

        // My 8 a(kb) loads landed (W(kb) was retired before the barrier).
        asm volatile("s_waitcnt vmcnt(0)" ::: "memory");
        __builtin_amdgcn_sched_barrier(0);

        // Next W DMA first: oldest vmem op -> bottom vmcnt(8) retires it.
        if (has_next) dma_w(cur ^ 1, kb + 1);

        // b ks0 half from LDS.
        short8 b0[4];
        #pragma unroll
        for (int nt = 0; nt < 4; ++nt)
            b0[nt] = *(const short8*)&Ws[cur][(nt * 16 + l15) * 64 + swA];
        asm volatile("s_waitcnt lgkmcnt(0)" ::: "memory");
        __builtin_amdgcn_sched_barrier(0);

        __builtin_amdgcn_s_setprio(1);
        #pragma unroll
        for (int mt = 0; mt < 4; ++mt)
            #pragma unroll
            for (int nt = 0; nt < 4; ++nt)
                acc[mt][nt] = __builtin_amdgcn_mfma_f32_16x16x32_bf16(
                    a0[mt], b0[nt], acc[mt][nt], 0, 0, 0);
        __builtin_amdgcn_s_setprio(0);
        __builtin_amdgcn_sched_barrier(0);

        // b ks1 half (b0 regs dead -> allocator reuses) + a0(kb+1) prefetch
        // (a0 regs freed by ks0 issue; WAR safe: loads issued after MFMAs).
        short8 b1[4];
        #pragma unroll
        for (int nt = 0; nt < 4; ++nt)
            b1[nt] = *(const short8*)&Ws[cur][(nt * 16 + l15) * 64 + swB];
        const unsigned short* xp = xrow + (size_t)(has_next ? ci[kb + 1] : 0) * 64;
        if (has_next) {
            #pragma unroll
            for (int mt = 0; mt < 4; ++mt)
                a0[mt] = *(const short8*)(xp + mt * 65536);
        }
        asm volatile("s_waitcnt lgkmcnt(0)" ::: "memory");
        __builtin_amdgcn_sched_barrier(0);

        __builtin_amdgcn_s_setprio(1);
        #pragma unroll
        for (int mt = 0; mt < 4; ++mt)
            #pragma unroll
            for (int nt = 0; nt < 4; ++nt)
                acc[mt][nt] = __builtin_amdgcn_mfma_f32_16x16x32_bf16(
                    a1[mt], b1[nt], acc[mt][nt], 0, 0, 0);
        __builtin_amdgcn_s_setprio(0);
        __builtin_amdgcn_sched_barrier(0);

        if (has_next) {
            #pragma unroll
            for (int mt = 0; mt < 4; ++mt)
                a1[mt] = *(const short8*)(xp + mt * 65536 + 32);
            // Outstanding: W(kb+1) + 8 a-loads = 9. Retire W only; the 8
            // a-loads survive the barrier and are waited at the next top.
            asm volatile("s_waitcnt vmcnt(8)" ::: "memory");
            __builtin_amdgcn_sched_barrier(0);
            __builtin_amdgcn_s_barrier();          // publish W(kb+1)
        }
    }

    // Epilogue: C/D layout col = lane&15, row = (lane>>4)*4 + reg.
    const int ocol0 = rb * 64;
    #pragma unroll
    for (int nt = 0; nt < 4; ++nt) {
        const int col = ocol0 + nt * 16 + l15;
        const float bv = bias[col];
        #pragma unroll
        for (int mt = 0; mt < 4; ++mt) {
            const size_t trow = (size_t)tok0 + wv * 64 + mt * 16 + l4 * 4;
            float* op = out + trow * 4096 + col;
            #pragma unroll
            for (int r = 0; r < 4; ++r)
                op[(size_t)r * 4096] = acc[mt][nt][r] + bv;
        }
    }
}

// ---- Fallback (fp32 direct) if ws too small ---- (256 threads, TM=256)
#define TMF 256
#define NTF 256
#define XS_LD 72
#define WS_LD 72
__global__ __launch_bounds__(NTF)
void bsl_mfma_f32_kernel(const float* __restrict__ x,
                         const float* __restrict__ w,
                         const float* __restrict__ bias,
                         const int* __restrict__ col_idx,
                         float* __restrict__ out)
{
    __shared__ unsigned short Xs[TMF * XS_LD];
    __shared__ unsigned short Ws[64 * WS_LD];
    const int rb = blockIdx.x, tt = blockIdx.y;
    const int tid = threadIdx.x, lane = tid & 63, wv = tid >> 6;
    const int l15 = lane & 15, l4 = lane >> 4, tok0 = tt * TMF;
    floatx4 acc[4][4];
    #pragma unroll
    for (int i = 0; i < 4; ++i)
        #pragma unroll
        for (int j = 0; j < 4; ++j) acc[i][j] = (floatx4){0.f,0.f,0.f,0.f};
    for (int kb = 0; kb < KNZ; ++kb) {
        const int nz = rb * KNZ + kb;
        const int cb = col_idx[nz];
        const float* xsrc = x + (size_t)tok0 * 4096 + (size_t)cb * 64;
        const float* wsrc = w + (size_t)nz * 4096;
        __syncthreads();
        #pragma unroll
        for (int i = 0; i < 16; ++i) {
            int f = i * NTF + tid, row = f >> 4, c4 = f & 15;
            floatx4 v = *(const floatx4*)(xsrc + (size_t)row * 4096 + c4 * 4);
            ushort4 p; p.x=f2bf(v.x); p.y=f2bf(v.y); p.z=f2bf(v.z); p.w=f2bf(v.w);
            *(ushort4*)&Xs[row * XS_LD + c4 * 4] = p;
        }
        #pragma unroll
        for (int i = 0; i < 4; ++i) {
            int f = i * NTF + tid, row = f >> 4, c4 = f & 15;
            floatx4 v = *(const floatx4*)(wsrc + row * 64 + c4 * 4);
            ushort4 p; p.x=f2bf(v.x); p.y=f2bf(v.y); p.z=f2bf(v.z); p.w=f2bf(v.w);
            *(ushort4*)&Ws[row * WS_LD + c4 * 4] = p;
        }
        __syncthreads();
        #pragma unroll
        for (int ks = 0; ks < 2; ++ks) {
            const int k0 = ks * 32 + l4 * 8;
            short8 a[4], b[4];
            #pragma unroll
            for (int mt = 0; mt < 4; ++mt)
                a[mt] = *(const short8*)&Xs[(wv*64 + mt*16 + l15) * XS_LD + k0];
            #pragma unroll
            for (int nt = 0; nt < 4; ++nt)
                b[nt] = *(const short8*)&Ws[(nt*16 + l15) * WS_LD + k0];
            #pragma unroll
            for (int mt = 0; mt < 4; ++mt)
                #pragma unroll
                for (int nt = 0; nt < 4; ++nt)
                    acc[mt][nt] = __builtin_amdgcn_mfma_f32_16x16x32_bf16(
                        a[mt], b[nt], acc[mt][nt], 0, 0, 0);
        }
    }
    const int ocol0 = rb * 64;
    #pragma unroll
    for (int nt = 0; nt < 4; ++nt) {
        const int col = ocol0 + nt * 16 + l15;
        const float bv = bias[col];
        #pragma unroll
        for (int mt = 0; mt < 4; ++mt) {
            const size_t trow = (size_t)tok0 + wv * 64 + mt * 16 + l4 * 4;
            float* op = out + trow * 4096 + col;
            #pragma unroll
            for (int r = 0; r < 4; ++r)
                op[(size_t)r * 4096] = acc[mt][nt][r] + bv;
        }
    }
}

extern "C" void kernel_launch(void* const* d_in, const int* in_sizes, int n_in,
                              void* d_out, int out_size, void* d_ws, size_t ws_size,
                              hipStream_t stream) {
    const float* x       = (const float*)d_in[0];
    const float* w       = (const float*)d_in[1];
    const float* bias    = (const float*)d_in[2];
    const int*   col_idx = (const int*)d_in[4];
    float*       out     = (float*)d_out;

    const int n_x = in_sizes[0];
    const int n_w = in_sizes[1];
    const int n_tok = n_x / 4096;
    const size_t need = (size_t)(n_x + n_w) * 2;

    if (ws_size >= need && (n_tok % TM) == 0) {
        unsigned short* xb = (unsigned short*)d_ws;
        unsigned short* wb = xb + n_x;
        int n_x8 = n_x / 8, n_w8 = n_w / 8;
        int total = n_x8 + n_w8;
        cvt_kernel<<<(total + CVT_THREADS - 1) / CVT_THREADS, CVT_THREADS, 0, stream>>>(
            x, w, xb, wb, n_x8, n_w8);
        int n_tiles = n_tok / TM;
        bsl_mfma_bf16_kernel<<<64 * n_tiles, NTHREADS, 0, stream>>>(
            xb, wb, bias, col_idx, out, n_tiles);
    } else {
        dim3 grid(64, n_tok / TMF);
        bsl_mfma_f32_kernel<<<grid, NTF, 0, stream>>>(x, w, bias, col_idx, out);
    }
}